// Round 1
// baseline (726.020 us; speedup 1.0000x reference)
//
#include <hip/hip_runtime.h>

#define D 128
#define NDRUG 20000
#define NDIS 20000
#define EDGES 640000
#define LROWS 200000

// ---------------- CSR build ----------------

__global__ __launch_bounds__(256) void hist_kernel(const int* __restrict__ dst,
                                                   int* __restrict__ cnt, int n) {
    int i = blockIdx.x * blockDim.x + threadIdx.x;
    if (i < n) atomicAdd(&cnt[dst[i]], 1);
}

// Single-block exclusive scan. cnt_io[i] (counts) -> start offsets (exclusive
// scan, used as scatter cursor); off[0..n] gets the full offset array.
__global__ __launch_bounds__(1024) void scan_kernel(int* __restrict__ cnt_io,
                                                    int* __restrict__ off, int n) {
    __shared__ int wsum[16];
    __shared__ int carry_s;
    const int tid = threadIdx.x;
    const int lane = tid & 63;
    const int wid = tid >> 6;
    if (tid == 0) { carry_s = 0; off[0] = 0; }
    __syncthreads();
    for (int start = 0; start < n; start += 1024) {
        int i = start + tid;
        int v = (i < n) ? cnt_io[i] : 0;
        int carry = carry_s;
        // inclusive scan within wave
        int s = v;
        #pragma unroll
        for (int o = 1; o < 64; o <<= 1) {
            int t = __shfl_up(s, o, 64);
            if (lane >= o) s += t;
        }
        if (lane == 63) wsum[wid] = s;
        __syncthreads();
        if (wid == 0) {
            int ws = (lane < 16) ? wsum[lane] : 0;
            #pragma unroll
            for (int o = 1; o < 16; o <<= 1) {
                int t = __shfl_up(ws, o, 64);
                if (lane >= o) ws += t;
            }
            if (lane < 16) wsum[lane] = ws;  // inclusive per-wave prefix
        }
        __syncthreads();
        int woff = (wid > 0) ? wsum[wid - 1] : 0;
        int incl = s + woff + carry;
        if (i < n) {
            off[i + 1] = incl;
            cnt_io[i] = incl - v;  // exclusive start (cursor)
        }
        __syncthreads();
        if (tid == 1023) carry_s = incl;
        __syncthreads();
    }
}

__global__ __launch_bounds__(256) void scatter_kernel(const int* __restrict__ src,
                                                      const int* __restrict__ dst,
                                                      int* __restrict__ cursor,
                                                      int* __restrict__ csr_src, int n) {
    int i = blockIdx.x * blockDim.x + threadIdx.x;
    if (i < n) {
        int d = dst[i];
        int pos = atomicAdd(&cursor[d], 1);
        csr_src[pos] = src[i];
    }
}

// ---------------- SAGE conv: out = mean_neigh(x_src) @ Wl + b + x_dst @ Wr ----------------
// One wave per NPW nodes; lane holds output dims (2*lane, 2*lane+1).

#define NPW 4

__global__ __launch_bounds__(256) void sage_kernel(
    const float* __restrict__ xsrc, const float* __restrict__ xdst,
    const int* __restrict__ off, const int* __restrict__ csr,
    const float* __restrict__ Wl, const float* __restrict__ Wr,
    const float* __restrict__ b, float* __restrict__ out,
    int ndst, int do_relu)
{
    __shared__ __align__(16) float lmean[4][NPW][D];
    __shared__ __align__(16) float ldst[4][NPW][D];
    const int lane = threadIdx.x & 63;
    const int wid = threadIdx.x >> 6;
    const int j0 = lane * 2;
    const int node0 = (blockIdx.x * 4 + wid) * NPW;

    // phase 1: mean aggregation + stage mean & x_dst rows in LDS
    for (int r = 0; r < NPW; ++r) {
        int node = node0 + r;
        if (node >= ndst) break;
        int e0 = off[node], e1 = off[node + 1];
        int deg = e1 - e0;
        float2 acc; acc.x = 0.f; acc.y = 0.f;
        int e = e0;
        for (; e + 4 <= e1; e += 4) {
            int s0 = csr[e], s1 = csr[e + 1], s2 = csr[e + 2], s3 = csr[e + 3];
            float2 v0 = *(const float2*)(xsrc + (size_t)s0 * D + j0);
            float2 v1 = *(const float2*)(xsrc + (size_t)s1 * D + j0);
            float2 v2 = *(const float2*)(xsrc + (size_t)s2 * D + j0);
            float2 v3 = *(const float2*)(xsrc + (size_t)s3 * D + j0);
            acc.x += v0.x + v1.x + v2.x + v3.x;
            acc.y += v0.y + v1.y + v2.y + v3.y;
        }
        for (; e < e1; ++e) {
            int s = csr[e];
            float2 v = *(const float2*)(xsrc + (size_t)s * D + j0);
            acc.x += v.x; acc.y += v.y;
        }
        float inv = 1.0f / (float)(deg < 1 ? 1 : deg);
        float2 xd = *(const float2*)(xdst + (size_t)node * D + j0);
        lmean[wid][r][j0] = acc.x * inv;
        lmean[wid][r][j0 + 1] = acc.y * inv;
        ldst[wid][r][j0] = xd.x;
        ldst[wid][r][j0 + 1] = xd.y;
    }
    __syncthreads();

    // phase 2: [NPW x 128] @ Wl + [NPW x 128] @ Wr
    float2 acc[NPW];
    float2 bv = *(const float2*)(b + j0);
    #pragma unroll
    for (int r = 0; r < NPW; ++r) acc[r] = bv;

    for (int k = 0; k < D; k += 2) {
        float2 wl0 = *(const float2*)(Wl + (size_t)k * D + j0);
        float2 wr0 = *(const float2*)(Wr + (size_t)k * D + j0);
        float2 wl1 = *(const float2*)(Wl + (size_t)(k + 1) * D + j0);
        float2 wr1 = *(const float2*)(Wr + (size_t)(k + 1) * D + j0);
        #pragma unroll
        for (int r = 0; r < NPW; ++r) {
            float2 m = *(const float2*)&lmean[wid][r][k];
            float2 dd = *(const float2*)&ldst[wid][r][k];
            acc[r].x = fmaf(m.x, wl0.x, acc[r].x);
            acc[r].y = fmaf(m.x, wl0.y, acc[r].y);
            acc[r].x = fmaf(dd.x, wr0.x, acc[r].x);
            acc[r].y = fmaf(dd.x, wr0.y, acc[r].y);
            acc[r].x = fmaf(m.y, wl1.x, acc[r].x);
            acc[r].y = fmaf(m.y, wl1.y, acc[r].y);
            acc[r].x = fmaf(dd.y, wr1.x, acc[r].x);
            acc[r].y = fmaf(dd.y, wr1.y, acc[r].y);
        }
    }

    for (int r = 0; r < NPW; ++r) {
        int node = node0 + r;
        if (node < ndst) {
            float2 o = acc[r];
            if (do_relu) { o.x = fmaxf(o.x, 0.f); o.y = fmaxf(o.y, 0.f); }
            *(float2*)(out + (size_t)node * D + j0) = o;
        }
    }
}

// ---------------- decoder: relu(concat(z_drug[row], z_dis[col]) @ W1 + b1) @ W2 + b2 ----------------

#define RPW 8

__global__ __launch_bounds__(256) void dec_kernel(
    const float* __restrict__ zdrug, const float* __restrict__ zdis,
    const int* __restrict__ row_idx, const int* __restrict__ col_idx,
    const float* __restrict__ W1, const float* __restrict__ b1,
    const float* __restrict__ W2, const float* __restrict__ b2,
    float* __restrict__ out, int nrows)
{
    __shared__ __align__(16) float la[4][RPW][2 * D];
    const int lane = threadIdx.x & 63;
    const int wid = threadIdx.x >> 6;
    const int j0 = lane * 2;
    const int r0 = (blockIdx.x * 4 + wid) * RPW;

    for (int r = 0; r < RPW; ++r) {
        int rr = r0 + r;
        if (rr < nrows) {
            int ri = row_idx[rr], ci = col_idx[rr];
            float2 a0 = *(const float2*)(zdrug + (size_t)ri * D + j0);
            float2 a1 = *(const float2*)(zdis + (size_t)ci * D + j0);
            la[wid][r][j0] = a0.x; la[wid][r][j0 + 1] = a0.y;
            la[wid][r][D + j0] = a1.x; la[wid][r][D + j0 + 1] = a1.y;
        } else {
            la[wid][r][j0] = 0.f; la[wid][r][j0 + 1] = 0.f;
            la[wid][r][D + j0] = 0.f; la[wid][r][D + j0 + 1] = 0.f;
        }
    }
    __syncthreads();

    float2 acc[RPW];
    float2 b1v = *(const float2*)(b1 + j0);
    #pragma unroll
    for (int r = 0; r < RPW; ++r) acc[r] = b1v;

    for (int k = 0; k < 2 * D; k += 2) {
        float2 w0 = *(const float2*)(W1 + (size_t)k * D + j0);
        float2 w1 = *(const float2*)(W1 + (size_t)(k + 1) * D + j0);
        #pragma unroll
        for (int r = 0; r < RPW; ++r) {
            float2 a = *(const float2*)&la[wid][r][k];
            acc[r].x = fmaf(a.x, w0.x, acc[r].x);
            acc[r].y = fmaf(a.x, w0.y, acc[r].y);
            acc[r].x = fmaf(a.y, w1.x, acc[r].x);
            acc[r].y = fmaf(a.y, w1.y, acc[r].y);
        }
    }

    float w2x = W2[j0], w2y = W2[j0 + 1];
    float b2v = b2[0];
    for (int r = 0; r < RPW; ++r) {
        float h0 = fmaxf(acc[r].x, 0.f);
        float h1 = fmaxf(acc[r].y, 0.f);
        float p = fmaf(h0, w2x, h1 * w2y);
        #pragma unroll
        for (int o = 32; o >= 1; o >>= 1) p += __shfl_xor(p, o, 64);
        int rr = r0 + r;
        if (lane == 0 && rr < nrows) out[rr] = p + b2v;
    }
}

// ---------------- launcher ----------------

extern "C" void kernel_launch(void* const* d_in, const int* in_sizes, int n_in,
                              void* d_out, int out_size, void* d_ws, size_t ws_size,
                              hipStream_t stream) {
    const float* x_drug = (const float*)d_in[0];
    const float* x_dis  = (const float*)d_in[1];
    const int* ei_d2s = (const int*)d_in[2];
    const int* ei_s2d = (const int*)d_in[3];
    const int* ell    = (const int*)d_in[4];
    const float* W1l_d2s = (const float*)d_in[5];
    const float* W1r_d2s = (const float*)d_in[6];
    const float* W1l_s2d = (const float*)d_in[7];
    const float* W1r_s2d = (const float*)d_in[8];
    const float* W2l_d2s = (const float*)d_in[9];
    const float* W2r_d2s = (const float*)d_in[10];
    const float* W2l_s2d = (const float*)d_in[11];
    const float* W2r_s2d = (const float*)d_in[12];
    const float* b1_d2s = (const float*)d_in[13];
    const float* b1_s2d = (const float*)d_in[14];
    const float* b2_d2s = (const float*)d_in[15];
    const float* b2_s2d = (const float*)d_in[16];
    const float* dec_W1 = (const float*)d_in[17];
    const float* dec_b1 = (const float*)d_in[18];
    const float* dec_W2 = (const float*)d_in[19];
    const float* dec_b2 = (const float*)d_in[20];
    float* out = (float*)d_out;

    char* ws = (char*)d_ws;
    size_t o = 0;
    auto take = [&](size_t bytes) -> char* {
        char* p = ws + o;
        o += (bytes + 255) & ~(size_t)255;
        return p;
    };
    int* off_d2s = (int*)take((NDIS + 1) * sizeof(int));
    int* cur_d2s = (int*)take(NDIS * sizeof(int));
    int* csr_d2s = (int*)take((size_t)EDGES * sizeof(int));
    int* off_s2d = (int*)take((NDRUG + 1) * sizeof(int));
    int* cur_s2d = (int*)take(NDRUG * sizeof(int));
    int* csr_s2d = (int*)take((size_t)EDGES * sizeof(int));
    float* h_dis  = (float*)take((size_t)NDIS * D * sizeof(float));
    float* h_drug = (float*)take((size_t)NDRUG * D * sizeof(float));
    float* z_dis  = (float*)take((size_t)NDIS * D * sizeof(float));
    float* z_drug = (float*)take((size_t)NDRUG * D * sizeof(float));

    hipMemsetAsync(cur_d2s, 0, NDIS * sizeof(int), stream);
    hipMemsetAsync(cur_s2d, 0, NDRUG * sizeof(int), stream);

    const int EB = (EDGES + 255) / 256;
    hist_kernel<<<EB, 256, 0, stream>>>(ei_d2s + EDGES, cur_d2s, EDGES);
    hist_kernel<<<EB, 256, 0, stream>>>(ei_s2d + EDGES, cur_s2d, EDGES);
    scan_kernel<<<1, 1024, 0, stream>>>(cur_d2s, off_d2s, NDIS);
    scan_kernel<<<1, 1024, 0, stream>>>(cur_s2d, off_s2d, NDRUG);
    scatter_kernel<<<EB, 256, 0, stream>>>(ei_d2s, ei_d2s + EDGES, cur_d2s, csr_d2s, EDGES);
    scatter_kernel<<<EB, 256, 0, stream>>>(ei_s2d, ei_s2d + EDGES, cur_s2d, csr_s2d, EDGES);

    // layer 1 (relu)
    sage_kernel<<<1250, 256, 0, stream>>>(x_drug, x_dis, off_d2s, csr_d2s,
                                          W1l_d2s, W1r_d2s, b1_d2s, h_dis, NDIS, 1);
    sage_kernel<<<1250, 256, 0, stream>>>(x_dis, x_drug, off_s2d, csr_s2d,
                                          W1l_s2d, W1r_s2d, b1_s2d, h_drug, NDRUG, 1);
    // layer 2 (no activation)
    sage_kernel<<<1250, 256, 0, stream>>>(h_drug, h_dis, off_d2s, csr_d2s,
                                          W2l_d2s, W2r_d2s, b2_d2s, z_dis, NDIS, 0);
    sage_kernel<<<1250, 256, 0, stream>>>(h_dis, h_drug, off_s2d, csr_s2d,
                                          W2l_s2d, W2r_s2d, b2_s2d, z_drug, NDRUG, 0);

    // decoder
    dec_kernel<<<6250, 256, 0, stream>>>(z_drug, z_dis, ell, ell + LROWS,
                                         dec_W1, dec_b1, dec_W2, dec_b2, out, LROWS);
}

// Round 2
// 649.505 us; speedup vs baseline: 1.1178x; 1.1178x over previous
//
#include <hip/hip_runtime.h>

#define D 128
#define NDRUG 20000
#define NDIS 20000
#define EDGES 640000
#define LROWS 200000

typedef unsigned short u16;
typedef __attribute__((ext_vector_type(8))) short s8v;
typedef __attribute__((ext_vector_type(4))) float f4v;

__device__ inline u16 f2bf_rne(float x) {
    unsigned u = __float_as_uint(x);
    unsigned r = u + 0x7FFFu + ((u >> 16) & 1u);
    return (u16)(r >> 16);
}
__device__ inline float bf2f(u16 h) {
    return __uint_as_float(((unsigned)h) << 16);
}
__device__ inline void split1(float x, u16& h, u16& l) {
    h = f2bf_rne(x);
    float r = x - bf2f(h);
    l = f2bf_rne(r);
}

// ---------------- CSR build ----------------

__global__ __launch_bounds__(256) void hist_kernel(const int* __restrict__ dst,
                                                   int* __restrict__ cnt, int n) {
    int i = blockIdx.x * blockDim.x + threadIdx.x;
    if (i < n) atomicAdd(&cnt[dst[i]], 1);
}

__global__ __launch_bounds__(1024) void scan_kernel(int* __restrict__ cnt_io,
                                                    int* __restrict__ off, int n) {
    __shared__ int wsum[16];
    __shared__ int carry_s;
    const int tid = threadIdx.x;
    const int lane = tid & 63;
    const int wid = tid >> 6;
    if (tid == 0) { carry_s = 0; off[0] = 0; }
    __syncthreads();
    for (int start = 0; start < n; start += 1024) {
        int i = start + tid;
        int v = (i < n) ? cnt_io[i] : 0;
        int carry = carry_s;
        int s = v;
        #pragma unroll
        for (int o = 1; o < 64; o <<= 1) {
            int t = __shfl_up(s, o, 64);
            if (lane >= o) s += t;
        }
        if (lane == 63) wsum[wid] = s;
        __syncthreads();
        if (wid == 0) {
            int ws = (lane < 16) ? wsum[lane] : 0;
            #pragma unroll
            for (int o = 1; o < 16; o <<= 1) {
                int t = __shfl_up(ws, o, 64);
                if (lane >= o) ws += t;
            }
            if (lane < 16) wsum[lane] = ws;
        }
        __syncthreads();
        int woff = (wid > 0) ? wsum[wid - 1] : 0;
        int incl = s + woff + carry;
        if (i < n) {
            off[i + 1] = incl;
            cnt_io[i] = incl - v;
        }
        __syncthreads();
        if (tid == 1023) carry_s = incl;
        __syncthreads();
    }
}

__global__ __launch_bounds__(256) void scatter_kernel(const int* __restrict__ src,
                                                      const int* __restrict__ dst,
                                                      int* __restrict__ cursor,
                                                      int* __restrict__ csr_src, int n) {
    int i = blockIdx.x * blockDim.x + threadIdx.x;
    if (i < n) {
        int d = dst[i];
        int pos = atomicAdd(&cursor[d], 1);
        csr_src[pos] = src[i];
    }
}

// ---------------- SAGE conv (unchanged from round 1) ----------------

#define NPW 4

__global__ __launch_bounds__(256) void sage_kernel(
    const float* __restrict__ xsrc, const float* __restrict__ xdst,
    const int* __restrict__ off, const int* __restrict__ csr,
    const float* __restrict__ Wl, const float* __restrict__ Wr,
    const float* __restrict__ b, float* __restrict__ out,
    int ndst, int do_relu)
{
    __shared__ __align__(16) float lmean[4][NPW][D];
    __shared__ __align__(16) float ldst[4][NPW][D];
    const int lane = threadIdx.x & 63;
    const int wid = threadIdx.x >> 6;
    const int j0 = lane * 2;
    const int node0 = (blockIdx.x * 4 + wid) * NPW;

    for (int r = 0; r < NPW; ++r) {
        int node = node0 + r;
        if (node >= ndst) break;
        int e0 = off[node], e1 = off[node + 1];
        int deg = e1 - e0;
        float2 acc; acc.x = 0.f; acc.y = 0.f;
        int e = e0;
        for (; e + 4 <= e1; e += 4) {
            int s0 = csr[e], s1 = csr[e + 1], s2 = csr[e + 2], s3 = csr[e + 3];
            float2 v0 = *(const float2*)(xsrc + (size_t)s0 * D + j0);
            float2 v1 = *(const float2*)(xsrc + (size_t)s1 * D + j0);
            float2 v2 = *(const float2*)(xsrc + (size_t)s2 * D + j0);
            float2 v3 = *(const float2*)(xsrc + (size_t)s3 * D + j0);
            acc.x += v0.x + v1.x + v2.x + v3.x;
            acc.y += v0.y + v1.y + v2.y + v3.y;
        }
        for (; e < e1; ++e) {
            int s = csr[e];
            float2 v = *(const float2*)(xsrc + (size_t)s * D + j0);
            acc.x += v.x; acc.y += v.y;
        }
        float inv = 1.0f / (float)(deg < 1 ? 1 : deg);
        float2 xd = *(const float2*)(xdst + (size_t)node * D + j0);
        lmean[wid][r][j0] = acc.x * inv;
        lmean[wid][r][j0 + 1] = acc.y * inv;
        ldst[wid][r][j0] = xd.x;
        ldst[wid][r][j0 + 1] = xd.y;
    }
    __syncthreads();

    float2 acc[NPW];
    float2 bv = *(const float2*)(b + j0);
    #pragma unroll
    for (int r = 0; r < NPW; ++r) acc[r] = bv;

    for (int k = 0; k < D; k += 2) {
        float2 wl0 = *(const float2*)(Wl + (size_t)k * D + j0);
        float2 wr0 = *(const float2*)(Wr + (size_t)k * D + j0);
        float2 wl1 = *(const float2*)(Wl + (size_t)(k + 1) * D + j0);
        float2 wr1 = *(const float2*)(Wr + (size_t)(k + 1) * D + j0);
        #pragma unroll
        for (int r = 0; r < NPW; ++r) {
            float2 m = *(const float2*)&lmean[wid][r][k];
            float2 dd = *(const float2*)&ldst[wid][r][k];
            acc[r].x = fmaf(m.x, wl0.x, acc[r].x);
            acc[r].y = fmaf(m.x, wl0.y, acc[r].y);
            acc[r].x = fmaf(dd.x, wr0.x, acc[r].x);
            acc[r].y = fmaf(dd.x, wr0.y, acc[r].y);
            acc[r].x = fmaf(m.y, wl1.x, acc[r].x);
            acc[r].y = fmaf(m.y, wl1.y, acc[r].y);
            acc[r].x = fmaf(dd.y, wr1.x, acc[r].x);
            acc[r].y = fmaf(dd.y, wr1.y, acc[r].y);
        }
    }

    for (int r = 0; r < NPW; ++r) {
        int node = node0 + r;
        if (node < ndst) {
            float2 o = acc[r];
            if (do_relu) { o.x = fmaxf(o.x, 0.f); o.y = fmaxf(o.y, 0.f); }
            *(float2*)(out + (size_t)node * D + j0) = o;
        }
    }
}

// ---------------- hi/lo bf16 split of a fp32 array (4 floats/thread) ----------------

__global__ __launch_bounds__(256) void split_kernel(const float* __restrict__ in,
                                                    u16* __restrict__ hi,
                                                    u16* __restrict__ lo, int n4) {
    int i = blockIdx.x * blockDim.x + threadIdx.x;
    if (i >= n4) return;
    float4 v = ((const float4*)in)[i];
    u16 h0, h1, h2, h3, l0, l1, l2, l3;
    split1(v.x, h0, l0); split1(v.y, h1, l1);
    split1(v.z, h2, l2); split1(v.w, h3, l3);
    ushort4 hv; hv.x = h0; hv.y = h1; hv.z = h2; hv.w = h3;
    ushort4 lv; lv.x = l0; lv.y = l1; lv.z = l2; lv.w = l3;
    ((ushort4*)hi)[i] = hv;
    ((ushort4*)lo)[i] = lv;
}

// transpose + split dec_W1 [256][128] -> Wt_{h,l} [128][256]
__global__ __launch_bounds__(256) void wprep_kernel(const float* __restrict__ W1,
                                                    u16* __restrict__ Wh,
                                                    u16* __restrict__ Wl) {
    int i = blockIdx.x * blockDim.x + threadIdx.x;  // i = c*256 + k
    if (i < 128 * 256) {
        int c = i >> 8;
        int k = i & 255;
        split1(W1[k * 128 + c], Wh[i], Wl[i]);
    }
}

// ---------------- decoder via bf16-split MFMA ----------------
// Block = 64 rows, 4 waves; wave w owns cols [32w, 32w+32).
// A row r = concat(z_drug[row[r]], z_dis[col[r]]), gathered directly from
// global as MFMA fragments (16B per lane).  h = A@W1+b1 -> relu -> dot W2.

__global__ __launch_bounds__(256) void dec_mfma_kernel(
    const u16* __restrict__ zdr_h, const u16* __restrict__ zdr_l,
    const u16* __restrict__ zds_h, const u16* __restrict__ zds_l,
    const int* __restrict__ row_idx, const int* __restrict__ col_idx,
    const u16* __restrict__ Wt_h, const u16* __restrict__ Wt_l,
    const float* __restrict__ b1, const float* __restrict__ W2,
    const float* __restrict__ b2, float* __restrict__ out)
{
    __shared__ float psum[64];
    const int tid = threadIdx.x;
    const int lane = tid & 63;
    const int wid = tid >> 6;
    const int g = lane >> 4;       // k-group 0..3
    const int lr = lane & 15;      // row (A) / col (B,D) within tile
    const int row_base = blockIdx.x * 64;

    if (tid < 64) psum[tid] = 0.f;

    int ridx[4], cidx[4];
    #pragma unroll
    for (int rt = 0; rt < 4; ++rt) {
        int r = row_base + rt * 16 + lr;
        ridx[rt] = row_idx[r];
        cidx[rt] = col_idx[r];
    }

    f4v acc[4][2];
    #pragma unroll
    for (int rt = 0; rt < 4; ++rt)
        #pragma unroll
        for (int c = 0; c < 2; ++c)
            acc[rt][c] = (f4v){0.f, 0.f, 0.f, 0.f};

    const int col0 = wid * 32;

    #pragma unroll
    for (int t = 0; t < 8; ++t) {
        const u16* th = (t < 4) ? zdr_h : zds_h;
        const u16* tl = (t < 4) ? zdr_l : zds_l;
        const int koff = (t & 3) * 32 + g * 8;   // k within the 128-wide table
        s8v ah[4], al[4];
        #pragma unroll
        for (int rt = 0; rt < 4; ++rt) {
            int idx = (t < 4) ? ridx[rt] : cidx[rt];
            ah[rt] = *(const s8v*)(th + (size_t)idx * D + koff);
            al[rt] = *(const s8v*)(tl + (size_t)idx * D + koff);
        }
        s8v bh[2], bl[2];
        #pragma unroll
        for (int c = 0; c < 2; ++c) {
            int col = col0 + c * 16 + lr;
            bh[c] = *(const s8v*)(Wt_h + (size_t)col * 256 + t * 32 + g * 8);
            bl[c] = *(const s8v*)(Wt_l + (size_t)col * 256 + t * 32 + g * 8);
        }
        #pragma unroll
        for (int rt = 0; rt < 4; ++rt) {
            #pragma unroll
            for (int c = 0; c < 2; ++c) {
                acc[rt][c] = __builtin_amdgcn_mfma_f32_16x16x32_bf16(ah[rt], bh[c], acc[rt][c], 0, 0, 0);
                acc[rt][c] = __builtin_amdgcn_mfma_f32_16x16x32_bf16(ah[rt], bl[c], acc[rt][c], 0, 0, 0);
                acc[rt][c] = __builtin_amdgcn_mfma_f32_16x16x32_bf16(al[rt], bh[c], acc[rt][c], 0, 0, 0);
            }
        }
    }
    __syncthreads();   // psum zero-init visible; accs done

    float b1v[2], w2v[2];
    #pragma unroll
    for (int c = 0; c < 2; ++c) {
        int col = col0 + c * 16 + lr;
        b1v[c] = b1[col];
        w2v[c] = W2[col];
    }
    #pragma unroll
    for (int rt = 0; rt < 4; ++rt) {
        #pragma unroll
        for (int reg = 0; reg < 4; ++reg) {
            float v = 0.f;
            #pragma unroll
            for (int c = 0; c < 2; ++c) {
                float h = acc[rt][c][reg] + b1v[c];
                v = fmaf(fmaxf(h, 0.f), w2v[c], v);
            }
            // reduce over the 16 lanes (lr) holding this row's cols
            v += __shfl_xor(v, 1, 64);
            v += __shfl_xor(v, 2, 64);
            v += __shfl_xor(v, 4, 64);
            v += __shfl_xor(v, 8, 64);
            if (lr == 0) atomicAdd(&psum[rt * 16 + g * 4 + reg], v);
        }
    }
    __syncthreads();
    if (tid < 64) out[row_base + tid] = psum[tid] + b2[0];
}

// ---------------- launcher ----------------

extern "C" void kernel_launch(void* const* d_in, const int* in_sizes, int n_in,
                              void* d_out, int out_size, void* d_ws, size_t ws_size,
                              hipStream_t stream) {
    const float* x_drug = (const float*)d_in[0];
    const float* x_dis  = (const float*)d_in[1];
    const int* ei_d2s = (const int*)d_in[2];
    const int* ei_s2d = (const int*)d_in[3];
    const int* ell    = (const int*)d_in[4];
    const float* W1l_d2s = (const float*)d_in[5];
    const float* W1r_d2s = (const float*)d_in[6];
    const float* W1l_s2d = (const float*)d_in[7];
    const float* W1r_s2d = (const float*)d_in[8];
    const float* W2l_d2s = (const float*)d_in[9];
    const float* W2r_d2s = (const float*)d_in[10];
    const float* W2l_s2d = (const float*)d_in[11];
    const float* W2r_s2d = (const float*)d_in[12];
    const float* b1_d2s = (const float*)d_in[13];
    const float* b1_s2d = (const float*)d_in[14];
    const float* b2_d2s = (const float*)d_in[15];
    const float* b2_s2d = (const float*)d_in[16];
    const float* dec_W1 = (const float*)d_in[17];
    const float* dec_b1 = (const float*)d_in[18];
    const float* dec_W2 = (const float*)d_in[19];
    const float* dec_b2 = (const float*)d_in[20];
    float* out = (float*)d_out;

    char* ws = (char*)d_ws;
    size_t o = 0;
    auto take = [&](size_t bytes) -> char* {
        char* p = ws + o;
        o += (bytes + 255) & ~(size_t)255;
        return p;
    };
    int* off_d2s = (int*)take((NDIS + 1) * sizeof(int));
    int* cur_d2s = (int*)take(NDIS * sizeof(int));
    int* csr_d2s = (int*)take((size_t)EDGES * sizeof(int));
    int* off_s2d = (int*)take((NDRUG + 1) * sizeof(int));
    int* cur_s2d = (int*)take(NDRUG * sizeof(int));
    int* csr_s2d = (int*)take((size_t)EDGES * sizeof(int));
    float* h_dis  = (float*)take((size_t)NDIS * D * sizeof(float));
    float* h_drug = (float*)take((size_t)NDRUG * D * sizeof(float));
    float* z_dis  = (float*)take((size_t)NDIS * D * sizeof(float));
    float* z_drug = (float*)take((size_t)NDRUG * D * sizeof(float));
    u16* Wt_h = (u16*)take((size_t)128 * 256 * sizeof(u16));
    u16* Wt_l = (u16*)take((size_t)128 * 256 * sizeof(u16));

    // z hi/lo splits overlay the (dead by then) layer-1 h buffers:
    // order: sage3 reads h_drug; sage4 reads h_dis; then splits overwrite them.
    u16* zds_h = (u16*)h_drug;                    // z_dis  hi  (5.12 MB)
    u16* zds_l = (u16*)h_drug + (size_t)NDIS * D; // z_dis  lo
    u16* zdr_h = (u16*)h_dis;                     // z_drug hi
    u16* zdr_l = (u16*)h_dis + (size_t)NDRUG * D; // z_drug lo

    hipMemsetAsync(cur_d2s, 0, NDIS * sizeof(int), stream);
    hipMemsetAsync(cur_s2d, 0, NDRUG * sizeof(int), stream);

    const int EB = (EDGES + 255) / 256;
    hist_kernel<<<EB, 256, 0, stream>>>(ei_d2s + EDGES, cur_d2s, EDGES);
    hist_kernel<<<EB, 256, 0, stream>>>(ei_s2d + EDGES, cur_s2d, EDGES);
    scan_kernel<<<1, 1024, 0, stream>>>(cur_d2s, off_d2s, NDIS);
    scan_kernel<<<1, 1024, 0, stream>>>(cur_s2d, off_s2d, NDRUG);
    scatter_kernel<<<EB, 256, 0, stream>>>(ei_d2s, ei_d2s + EDGES, cur_d2s, csr_d2s, EDGES);
    scatter_kernel<<<EB, 256, 0, stream>>>(ei_s2d, ei_s2d + EDGES, cur_s2d, csr_s2d, EDGES);

    // decoder weight prep (independent of graph work)
    wprep_kernel<<<128, 256, 0, stream>>>(dec_W1, Wt_h, Wt_l);

    // layer 1 (relu)
    sage_kernel<<<1250, 256, 0, stream>>>(x_drug, x_dis, off_d2s, csr_d2s,
                                          W1l_d2s, W1r_d2s, b1_d2s, h_dis, NDIS, 1);
    sage_kernel<<<1250, 256, 0, stream>>>(x_dis, x_drug, off_s2d, csr_s2d,
                                          W1l_s2d, W1r_s2d, b1_s2d, h_drug, NDRUG, 1);
    // layer 2 (no activation)
    sage_kernel<<<1250, 256, 0, stream>>>(h_drug, h_dis, off_d2s, csr_d2s,
                                          W2l_d2s, W2r_d2s, b2_d2s, z_dis, NDIS, 0);
    sage_kernel<<<1250, 256, 0, stream>>>(h_dis, h_drug, off_s2d, csr_s2d,
                                          W2l_s2d, W2r_s2d, b2_s2d, z_drug, NDRUG, 0);

    // split z into hi/lo bf16 (overlays h buffers — both sages above are done)
    split_kernel<<<2500, 256, 0, stream>>>(z_dis, zds_h, zds_l, NDIS * D / 4);
    split_kernel<<<2500, 256, 0, stream>>>(z_drug, zdr_h, zdr_l, NDRUG * D / 4);

    // decoder: 200000/64 = 3125 blocks exactly
    dec_mfma_kernel<<<3125, 256, 0, stream>>>(zdr_h, zdr_l, zds_h, zds_l,
                                              ell, ell + LROWS, Wt_h, Wt_l,
                                              dec_b1, dec_W2, dec_b2, out);
}

// Round 3
// 593.646 us; speedup vs baseline: 1.2230x; 1.0941x over previous
//
#include <hip/hip_runtime.h>

#define D 128
#define NDRUG 20000
#define NDIS 20000
#define EDGES 640000
#define LROWS 200000

typedef unsigned short u16;
typedef __attribute__((ext_vector_type(8))) short s8v;
typedef __attribute__((ext_vector_type(4))) float f4v;

__device__ inline u16 f2bf_rne(float x) {
    unsigned u = __float_as_uint(x);
    unsigned r = u + 0x7FFFu + ((u >> 16) & 1u);
    return (u16)(r >> 16);
}
__device__ inline float bf2f(u16 h) {
    return __uint_as_float(((unsigned)h) << 16);
}
__device__ inline void split1(float x, u16& h, u16& l) {
    h = f2bf_rne(x);
    float r = x - bf2f(h);
    l = f2bf_rne(r);
}

// ---------------- CSR build ----------------

__global__ __launch_bounds__(256) void hist_kernel(const int* __restrict__ dst,
                                                   int* __restrict__ cnt, int n) {
    int i = blockIdx.x * blockDim.x + threadIdx.x;
    if (i < n) atomicAdd(&cnt[dst[i]], 1);
}

// Two independent single-block scans run as 2 blocks of one kernel.
__global__ __launch_bounds__(1024) void scan2_kernel(int* __restrict__ c0, int* __restrict__ o0,
                                                     int* __restrict__ c1, int* __restrict__ o1,
                                                     int n) {
    int* cnt_io = (blockIdx.x == 0) ? c0 : c1;
    int* off    = (blockIdx.x == 0) ? o0 : o1;
    __shared__ int wsum[16];
    __shared__ int carry_s;
    const int tid = threadIdx.x;
    const int lane = tid & 63;
    const int wid = tid >> 6;
    if (tid == 0) { carry_s = 0; off[0] = 0; }
    __syncthreads();
    for (int start = 0; start < n; start += 1024) {
        int i = start + tid;
        int v = (i < n) ? cnt_io[i] : 0;
        int carry = carry_s;
        int s = v;
        #pragma unroll
        for (int o = 1; o < 64; o <<= 1) {
            int t = __shfl_up(s, o, 64);
            if (lane >= o) s += t;
        }
        if (lane == 63) wsum[wid] = s;
        __syncthreads();
        if (wid == 0) {
            int ws = (lane < 16) ? wsum[lane] : 0;
            #pragma unroll
            for (int o = 1; o < 16; o <<= 1) {
                int t = __shfl_up(ws, o, 64);
                if (lane >= o) ws += t;
            }
            if (lane < 16) wsum[lane] = ws;
        }
        __syncthreads();
        int woff = (wid > 0) ? wsum[wid - 1] : 0;
        int incl = s + woff + carry;
        if (i < n) {
            off[i + 1] = incl;
            cnt_io[i] = incl - v;
        }
        __syncthreads();
        if (tid == 1023) carry_s = incl;
        __syncthreads();
    }
}

__global__ __launch_bounds__(256) void scatter_kernel(const int* __restrict__ src,
                                                      const int* __restrict__ dst,
                                                      int* __restrict__ cursor,
                                                      int* __restrict__ csr_src, int n) {
    int i = blockIdx.x * blockDim.x + threadIdx.x;
    if (i < n) {
        int d = dst[i];
        int pos = atomicAdd(&cursor[d], 1);
        csr_src[pos] = src[i];
    }
}

// ---------------- SAGE conv ----------------
// Phase 1 gather: coalesced index load + readlane broadcast -> scalar-based
// row addresses, 8 independent row loads in flight per iteration.

#define NPW 4

__global__ __launch_bounds__(256) void sage_kernel(
    const float* __restrict__ xsrc, const float* __restrict__ xdst,
    const int* __restrict__ off, const int* __restrict__ csr,
    const float* __restrict__ Wl, const float* __restrict__ Wr,
    const float* __restrict__ b, float* __restrict__ out,
    int ndst, int do_relu)
{
    __shared__ __align__(16) float lmean[4][NPW][D];
    __shared__ __align__(16) float ldst[4][NPW][D];
    const int lane = threadIdx.x & 63;
    const int wid = threadIdx.x >> 6;
    const int j0 = lane * 2;
    const int node0 = (blockIdx.x * 4 + wid) * NPW;

    for (int r = 0; r < NPW; ++r) {
        int node = node0 + r;
        if (node >= ndst) break;
        int e0 = off[node], e1 = off[node + 1];
        int deg = e1 - e0;
        float2 acc; acc.x = 0.f; acc.y = 0.f;
        for (int base = e0; base < e1; base += 64) {
            int rem = e1 - base;
            int nv = rem < 64 ? rem : 64;
            int myidx = 0;
            if (lane < nv) myidx = csr[base + lane];
            int e = 0;
            int full = nv & ~7;
            for (; e < full; e += 8) {
                int s0 = __builtin_amdgcn_readlane(myidx, e + 0);
                int s1 = __builtin_amdgcn_readlane(myidx, e + 1);
                int s2 = __builtin_amdgcn_readlane(myidx, e + 2);
                int s3 = __builtin_amdgcn_readlane(myidx, e + 3);
                int s4 = __builtin_amdgcn_readlane(myidx, e + 4);
                int s5 = __builtin_amdgcn_readlane(myidx, e + 5);
                int s6 = __builtin_amdgcn_readlane(myidx, e + 6);
                int s7 = __builtin_amdgcn_readlane(myidx, e + 7);
                float2 v0 = *(const float2*)(xsrc + (size_t)s0 * D + j0);
                float2 v1 = *(const float2*)(xsrc + (size_t)s1 * D + j0);
                float2 v2 = *(const float2*)(xsrc + (size_t)s2 * D + j0);
                float2 v3 = *(const float2*)(xsrc + (size_t)s3 * D + j0);
                float2 v4 = *(const float2*)(xsrc + (size_t)s4 * D + j0);
                float2 v5 = *(const float2*)(xsrc + (size_t)s5 * D + j0);
                float2 v6 = *(const float2*)(xsrc + (size_t)s6 * D + j0);
                float2 v7 = *(const float2*)(xsrc + (size_t)s7 * D + j0);
                float tx = ((v0.x + v1.x) + (v2.x + v3.x)) + ((v4.x + v5.x) + (v6.x + v7.x));
                float ty = ((v0.y + v1.y) + (v2.y + v3.y)) + ((v4.y + v5.y) + (v6.y + v7.y));
                acc.x += tx; acc.y += ty;
            }
            for (; e < nv; ++e) {
                int s = __builtin_amdgcn_readlane(myidx, e);
                float2 v = *(const float2*)(xsrc + (size_t)s * D + j0);
                acc.x += v.x; acc.y += v.y;
            }
        }
        float inv = 1.0f / (float)(deg < 1 ? 1 : deg);
        float2 xd = *(const float2*)(xdst + (size_t)node * D + j0);
        lmean[wid][r][j0] = acc.x * inv;
        lmean[wid][r][j0 + 1] = acc.y * inv;
        ldst[wid][r][j0] = xd.x;
        ldst[wid][r][j0 + 1] = xd.y;
    }
    __syncthreads();

    float2 acc[NPW];
    float2 bv = *(const float2*)(b + j0);
    #pragma unroll
    for (int r = 0; r < NPW; ++r) acc[r] = bv;

    for (int k = 0; k < D; k += 2) {
        float2 wl0 = *(const float2*)(Wl + (size_t)k * D + j0);
        float2 wr0 = *(const float2*)(Wr + (size_t)k * D + j0);
        float2 wl1 = *(const float2*)(Wl + (size_t)(k + 1) * D + j0);
        float2 wr1 = *(const float2*)(Wr + (size_t)(k + 1) * D + j0);
        #pragma unroll
        for (int r = 0; r < NPW; ++r) {
            float2 m = *(const float2*)&lmean[wid][r][k];
            float2 dd = *(const float2*)&ldst[wid][r][k];
            acc[r].x = fmaf(m.x, wl0.x, acc[r].x);
            acc[r].y = fmaf(m.x, wl0.y, acc[r].y);
            acc[r].x = fmaf(dd.x, wr0.x, acc[r].x);
            acc[r].y = fmaf(dd.x, wr0.y, acc[r].y);
            acc[r].x = fmaf(m.y, wl1.x, acc[r].x);
            acc[r].y = fmaf(m.y, wl1.y, acc[r].y);
            acc[r].x = fmaf(dd.y, wr1.x, acc[r].x);
            acc[r].y = fmaf(dd.y, wr1.y, acc[r].y);
        }
    }

    for (int r = 0; r < NPW; ++r) {
        int node = node0 + r;
        if (node < ndst) {
            float2 o = acc[r];
            if (do_relu) { o.x = fmaxf(o.x, 0.f); o.y = fmaxf(o.y, 0.f); }
            *(float2*)(out + (size_t)node * D + j0) = o;
        }
    }
}

// ---------------- hi/lo bf16 split ----------------

__global__ __launch_bounds__(256) void split_kernel(const float* __restrict__ in,
                                                    u16* __restrict__ hi,
                                                    u16* __restrict__ lo, int n4) {
    int i = blockIdx.x * blockDim.x + threadIdx.x;
    if (i >= n4) return;
    float4 v = ((const float4*)in)[i];
    u16 h0, h1, h2, h3, l0, l1, l2, l3;
    split1(v.x, h0, l0); split1(v.y, h1, l1);
    split1(v.z, h2, l2); split1(v.w, h3, l3);
    ushort4 hv; hv.x = h0; hv.y = h1; hv.z = h2; hv.w = h3;
    ushort4 lv; lv.x = l0; lv.y = l1; lv.z = l2; lv.w = l3;
    ((ushort4*)hi)[i] = hv;
    ((ushort4*)lo)[i] = lv;
}

// transpose + split dec_W1 [256][128] -> Wt_{h,l} [128][256]
__global__ __launch_bounds__(256) void wprep_kernel(const float* __restrict__ W1,
                                                    u16* __restrict__ Wh,
                                                    u16* __restrict__ Wl) {
    int i = blockIdx.x * blockDim.x + threadIdx.x;  // i = c*256 + k
    if (i < 128 * 256) {
        int c = i >> 8;
        int k = i & 255;
        split1(W1[k * 128 + c], Wh[i], Wl[i]);
    }
}

// ---------------- decoder via bf16-split MFMA ----------------
// Block = 128 rows, 4 waves; wave w owns rows [32w, 32w+32) x ALL 128 cols.
// No A redundancy across waves, no atomics: each wave completes its rows.

#define DROWS 128

__global__ __launch_bounds__(256) void dec_mfma_kernel(
    const u16* __restrict__ zdr_h, const u16* __restrict__ zdr_l,
    const u16* __restrict__ zds_h, const u16* __restrict__ zds_l,
    const int* __restrict__ row_idx, const int* __restrict__ col_idx,
    const u16* __restrict__ Wt_h, const u16* __restrict__ Wt_l,
    const float* __restrict__ b1, const float* __restrict__ W2,
    const float* __restrict__ b2, float* __restrict__ out, int nrows)
{
    const int tid = threadIdx.x;
    const int lane = tid & 63;
    const int wid = tid >> 6;
    const int g = lane >> 4;       // k-group / D-row-group
    const int lr = lane & 15;      // A-row / B-col within tile
    const int wrow0 = blockIdx.x * DROWS + wid * 32;

    int ridx[2], cidx[2];
    #pragma unroll
    for (int rt = 0; rt < 2; ++rt) {
        int r = wrow0 + rt * 16 + lr;
        r = (r < nrows) ? r : (nrows - 1);
        ridx[rt] = row_idx[r];
        cidx[rt] = col_idx[r];
    }

    f4v acc[2][8];
    #pragma unroll
    for (int rt = 0; rt < 2; ++rt)
        #pragma unroll
        for (int c = 0; c < 8; ++c)
            acc[rt][c] = (f4v){0.f, 0.f, 0.f, 0.f};

    #pragma unroll
    for (int t = 0; t < 8; ++t) {
        const u16* th = (t < 4) ? zdr_h : zds_h;
        const u16* tl = (t < 4) ? zdr_l : zds_l;
        const int koff = (t & 3) * 32 + g * 8;
        s8v ah[2], al[2];
        #pragma unroll
        for (int rt = 0; rt < 2; ++rt) {
            int idx = (t < 4) ? ridx[rt] : cidx[rt];
            ah[rt] = *(const s8v*)(th + (size_t)idx * D + koff);
            al[rt] = *(const s8v*)(tl + (size_t)idx * D + koff);
        }
        #pragma unroll
        for (int c = 0; c < 8; ++c) {
            int col = c * 16 + lr;
            s8v bh = *(const s8v*)(Wt_h + (size_t)col * 256 + t * 32 + g * 8);
            s8v bl = *(const s8v*)(Wt_l + (size_t)col * 256 + t * 32 + g * 8);
            #pragma unroll
            for (int rt = 0; rt < 2; ++rt) {
                acc[rt][c] = __builtin_amdgcn_mfma_f32_16x16x32_bf16(ah[rt], bh, acc[rt][c], 0, 0, 0);
                acc[rt][c] = __builtin_amdgcn_mfma_f32_16x16x32_bf16(ah[rt], bl, acc[rt][c], 0, 0, 0);
                acc[rt][c] = __builtin_amdgcn_mfma_f32_16x16x32_bf16(al[rt], bh, acc[rt][c], 0, 0, 0);
            }
        }
    }

    float b2v = b2[0];
    #pragma unroll
    for (int rt = 0; rt < 2; ++rt) {
        #pragma unroll
        for (int reg = 0; reg < 4; ++reg) {
            float v = 0.f;
            #pragma unroll
            for (int c = 0; c < 8; ++c) {
                int col = c * 16 + lr;
                float h = acc[rt][c][reg] + b1[col];
                v = fmaf(fmaxf(h, 0.f), W2[col], v);
            }
            v += __shfl_xor(v, 1, 64);
            v += __shfl_xor(v, 2, 64);
            v += __shfl_xor(v, 4, 64);
            v += __shfl_xor(v, 8, 64);
            int orow = wrow0 + rt * 16 + g * 4 + reg;
            if (lr == 0 && orow < nrows) out[orow] = v + b2v;
        }
    }
}

// ---------------- launcher ----------------

extern "C" void kernel_launch(void* const* d_in, const int* in_sizes, int n_in,
                              void* d_out, int out_size, void* d_ws, size_t ws_size,
                              hipStream_t stream) {
    const float* x_drug = (const float*)d_in[0];
    const float* x_dis  = (const float*)d_in[1];
    const int* ei_d2s = (const int*)d_in[2];
    const int* ei_s2d = (const int*)d_in[3];
    const int* ell    = (const int*)d_in[4];
    const float* W1l_d2s = (const float*)d_in[5];
    const float* W1r_d2s = (const float*)d_in[6];
    const float* W1l_s2d = (const float*)d_in[7];
    const float* W1r_s2d = (const float*)d_in[8];
    const float* W2l_d2s = (const float*)d_in[9];
    const float* W2r_d2s = (const float*)d_in[10];
    const float* W2l_s2d = (const float*)d_in[11];
    const float* W2r_s2d = (const float*)d_in[12];
    const float* b1_d2s = (const float*)d_in[13];
    const float* b1_s2d = (const float*)d_in[14];
    const float* b2_d2s = (const float*)d_in[15];
    const float* b2_s2d = (const float*)d_in[16];
    const float* dec_W1 = (const float*)d_in[17];
    const float* dec_b1 = (const float*)d_in[18];
    const float* dec_W2 = (const float*)d_in[19];
    const float* dec_b2 = (const float*)d_in[20];
    float* out = (float*)d_out;

    char* ws = (char*)d_ws;
    size_t o = 0;
    auto take = [&](size_t bytes) -> char* {
        char* p = ws + o;
        o += (bytes + 255) & ~(size_t)255;
        return p;
    };
    int* off_d2s = (int*)take((NDIS + 1) * sizeof(int));
    int* cur_d2s = (int*)take(NDIS * sizeof(int));
    int* csr_d2s = (int*)take((size_t)EDGES * sizeof(int));
    int* off_s2d = (int*)take((NDRUG + 1) * sizeof(int));
    int* cur_s2d = (int*)take(NDRUG * sizeof(int));
    int* csr_s2d = (int*)take((size_t)EDGES * sizeof(int));
    float* h_dis  = (float*)take((size_t)NDIS * D * sizeof(float));
    float* h_drug = (float*)take((size_t)NDRUG * D * sizeof(float));
    float* z_dis  = (float*)take((size_t)NDIS * D * sizeof(float));
    float* z_drug = (float*)take((size_t)NDRUG * D * sizeof(float));
    u16* Wt_h = (u16*)take((size_t)128 * 256 * sizeof(u16));
    u16* Wt_l = (u16*)take((size_t)128 * 256 * sizeof(u16));

    // z hi/lo splits overlay the (dead by then) layer-1 h buffers.
    u16* zds_h = (u16*)h_drug;
    u16* zds_l = (u16*)h_drug + (size_t)NDIS * D;
    u16* zdr_h = (u16*)h_dis;
    u16* zdr_l = (u16*)h_dis + (size_t)NDRUG * D;

    hipMemsetAsync(cur_d2s, 0, NDIS * sizeof(int), stream);
    hipMemsetAsync(cur_s2d, 0, NDRUG * sizeof(int), stream);

    const int EB = (EDGES + 255) / 256;
    hist_kernel<<<EB, 256, 0, stream>>>(ei_d2s + EDGES, cur_d2s, EDGES);
    hist_kernel<<<EB, 256, 0, stream>>>(ei_s2d + EDGES, cur_s2d, EDGES);
    scan2_kernel<<<2, 1024, 0, stream>>>(cur_d2s, off_d2s, cur_s2d, off_s2d, NDIS);
    scatter_kernel<<<EB, 256, 0, stream>>>(ei_d2s, ei_d2s + EDGES, cur_d2s, csr_d2s, EDGES);
    scatter_kernel<<<EB, 256, 0, stream>>>(ei_s2d, ei_s2d + EDGES, cur_s2d, csr_s2d, EDGES);

    wprep_kernel<<<128, 256, 0, stream>>>(dec_W1, Wt_h, Wt_l);

    // layer 1 (relu)
    sage_kernel<<<1250, 256, 0, stream>>>(x_drug, x_dis, off_d2s, csr_d2s,
                                          W1l_d2s, W1r_d2s, b1_d2s, h_dis, NDIS, 1);
    sage_kernel<<<1250, 256, 0, stream>>>(x_dis, x_drug, off_s2d, csr_s2d,
                                          W1l_s2d, W1r_s2d, b1_s2d, h_drug, NDRUG, 1);
    // layer 2 (no activation)
    sage_kernel<<<1250, 256, 0, stream>>>(h_drug, h_dis, off_d2s, csr_d2s,
                                          W2l_d2s, W2r_d2s, b2_d2s, z_dis, NDIS, 0);
    sage_kernel<<<1250, 256, 0, stream>>>(h_dis, h_drug, off_s2d, csr_s2d,
                                          W2l_s2d, W2r_s2d, b2_s2d, z_drug, NDRUG, 0);

    // split z into hi/lo bf16 (h buffers dead by now)
    split_kernel<<<2500, 256, 0, stream>>>(z_dis, zds_h, zds_l, NDIS * D / 4);
    split_kernel<<<2500, 256, 0, stream>>>(z_drug, zdr_h, zdr_l, NDRUG * D / 4);

    // decoder: ceil(200000/128) = 1563 blocks
    dec_mfma_kernel<<<(LROWS + DROWS - 1) / DROWS, 256, 0, stream>>>(
        zdr_h, zdr_l, zds_h, zds_l, ell, ell + LROWS, Wt_h, Wt_l,
        dec_b1, dec_W2, dec_b2, out, LROWS);
}

// Round 4
// 464.884 us; speedup vs baseline: 1.5617x; 1.2770x over previous
//
#include <hip/hip_runtime.h>
#include <hip/hip_fp16.h>

#define D 128
#define NDRUG 20000
#define NDIS 20000
#define EDGES 640000
#define LROWS 200000

// ---------------- CSR build ----------------

__global__ __launch_bounds__(256) void hist_kernel(const int* __restrict__ dst,
                                                   int* __restrict__ cnt, int n) {
    int i = blockIdx.x * blockDim.x + threadIdx.x;
    if (i < n) atomicAdd(&cnt[dst[i]], 1);
}

__global__ __launch_bounds__(1024) void scan2_kernel(int* __restrict__ c0, int* __restrict__ o0,
                                                     int* __restrict__ c1, int* __restrict__ o1,
                                                     int n) {
    int* cnt_io = (blockIdx.x == 0) ? c0 : c1;
    int* off    = (blockIdx.x == 0) ? o0 : o1;
    __shared__ int wsum[16];
    __shared__ int carry_s;
    const int tid = threadIdx.x;
    const int lane = tid & 63;
    const int wid = tid >> 6;
    if (tid == 0) { carry_s = 0; off[0] = 0; }
    __syncthreads();
    for (int start = 0; start < n; start += 1024) {
        int i = start + tid;
        int v = (i < n) ? cnt_io[i] : 0;
        int carry = carry_s;
        int s = v;
        #pragma unroll
        for (int o = 1; o < 64; o <<= 1) {
            int t = __shfl_up(s, o, 64);
            if (lane >= o) s += t;
        }
        if (lane == 63) wsum[wid] = s;
        __syncthreads();
        if (wid == 0) {
            int ws = (lane < 16) ? wsum[lane] : 0;
            #pragma unroll
            for (int o = 1; o < 16; o <<= 1) {
                int t = __shfl_up(ws, o, 64);
                if (lane >= o) ws += t;
            }
            if (lane < 16) wsum[lane] = ws;
        }
        __syncthreads();
        int woff = (wid > 0) ? wsum[wid - 1] : 0;
        int incl = s + woff + carry;
        if (i < n) {
            off[i + 1] = incl;
            cnt_io[i] = incl - v;
        }
        __syncthreads();
        if (tid == 1023) carry_s = incl;
        __syncthreads();
    }
}

__global__ __launch_bounds__(256) void scatter_kernel(const int* __restrict__ src,
                                                      const int* __restrict__ dst,
                                                      int* __restrict__ cursor,
                                                      int* __restrict__ csr_src, int n) {
    int i = blockIdx.x * blockDim.x + threadIdx.x;
    if (i < n) {
        int d = dst[i];
        int pos = atomicAdd(&cursor[d], 1);
        csr_src[pos] = src[i];
    }
}

// ---------------- fp32 -> fp16 table conversion ----------------

__global__ __launch_bounds__(256) void cvt16_kernel(const float* __restrict__ in,
                                                    __half* __restrict__ out, int n4) {
    int i = blockIdx.x * blockDim.x + threadIdx.x;
    if (i >= n4) return;
    float4 v = ((const float4*)in)[i];
    __half2 a = __floats2half2_rn(v.x, v.y);
    __half2 b = __floats2half2_rn(v.z, v.w);
    uint2 u;
    u.x = *(unsigned*)&a;
    u.y = *(unsigned*)&b;
    ((uint2*)out)[i] = u;
}

// ---------------- SAGE conv, fp16 tables ----------------
// gather fp16 rows (256B/row), fp32 accumulate + matmul.

#define NPW 4

// Layer 1: out16 = relu(mean @ Wl + b + xdst @ Wr), stored fp16.
__global__ __launch_bounds__(256) void sage_l1_kernel(
    const __half* __restrict__ xsrc, const __half* __restrict__ xdst,
    const int* __restrict__ off, const int* __restrict__ csr,
    const float* __restrict__ Wl, const float* __restrict__ Wr,
    const float* __restrict__ b, __half* __restrict__ out16, int ndst)
{
    __shared__ __align__(16) float lmean[4][NPW][D];
    __shared__ __align__(16) float ldst[4][NPW][D];
    const int lane = threadIdx.x & 63;
    const int wid = threadIdx.x >> 6;
    const int j0 = lane * 2;
    const int node0 = (blockIdx.x * 4 + wid) * NPW;

    for (int r = 0; r < NPW; ++r) {
        int node = node0 + r;
        if (node >= ndst) break;
        int e0 = off[node], e1 = off[node + 1];
        int deg = e1 - e0;
        float2 acc; acc.x = 0.f; acc.y = 0.f;
        for (int base = e0; base < e1; base += 64) {
            int rem = e1 - base;
            int nv = rem < 64 ? rem : 64;
            int myidx = 0;
            if (lane < nv) myidx = csr[base + lane];
            int e = 0;
            int full = nv & ~7;
            for (; e < full; e += 8) {
                int s0 = __builtin_amdgcn_readlane(myidx, e + 0);
                int s1 = __builtin_amdgcn_readlane(myidx, e + 1);
                int s2 = __builtin_amdgcn_readlane(myidx, e + 2);
                int s3 = __builtin_amdgcn_readlane(myidx, e + 3);
                int s4 = __builtin_amdgcn_readlane(myidx, e + 4);
                int s5 = __builtin_amdgcn_readlane(myidx, e + 5);
                int s6 = __builtin_amdgcn_readlane(myidx, e + 6);
                int s7 = __builtin_amdgcn_readlane(myidx, e + 7);
                float2 v0 = __half22float2(*(const __half2*)(xsrc + (size_t)s0 * D + j0));
                float2 v1 = __half22float2(*(const __half2*)(xsrc + (size_t)s1 * D + j0));
                float2 v2 = __half22float2(*(const __half2*)(xsrc + (size_t)s2 * D + j0));
                float2 v3 = __half22float2(*(const __half2*)(xsrc + (size_t)s3 * D + j0));
                float2 v4 = __half22float2(*(const __half2*)(xsrc + (size_t)s4 * D + j0));
                float2 v5 = __half22float2(*(const __half2*)(xsrc + (size_t)s5 * D + j0));
                float2 v6 = __half22float2(*(const __half2*)(xsrc + (size_t)s6 * D + j0));
                float2 v7 = __half22float2(*(const __half2*)(xsrc + (size_t)s7 * D + j0));
                acc.x += ((v0.x + v1.x) + (v2.x + v3.x)) + ((v4.x + v5.x) + (v6.x + v7.x));
                acc.y += ((v0.y + v1.y) + (v2.y + v3.y)) + ((v4.y + v5.y) + (v6.y + v7.y));
            }
            for (; e < nv; ++e) {
                int s = __builtin_amdgcn_readlane(myidx, e);
                float2 v = __half22float2(*(const __half2*)(xsrc + (size_t)s * D + j0));
                acc.x += v.x; acc.y += v.y;
            }
        }
        float inv = 1.0f / (float)(deg < 1 ? 1 : deg);
        float2 xd = __half22float2(*(const __half2*)(xdst + (size_t)node * D + j0));
        lmean[wid][r][j0] = acc.x * inv;
        lmean[wid][r][j0 + 1] = acc.y * inv;
        ldst[wid][r][j0] = xd.x;
        ldst[wid][r][j0 + 1] = xd.y;
    }
    __syncthreads();

    float2 acc[NPW];
    float2 bv = *(const float2*)(b + j0);
    #pragma unroll
    for (int r = 0; r < NPW; ++r) acc[r] = bv;

    for (int k = 0; k < D; k += 2) {
        float2 wl0 = *(const float2*)(Wl + (size_t)k * D + j0);
        float2 wr0 = *(const float2*)(Wr + (size_t)k * D + j0);
        float2 wl1 = *(const float2*)(Wl + (size_t)(k + 1) * D + j0);
        float2 wr1 = *(const float2*)(Wr + (size_t)(k + 1) * D + j0);
        #pragma unroll
        for (int r = 0; r < NPW; ++r) {
            float2 m = *(const float2*)&lmean[wid][r][k];
            float2 dd = *(const float2*)&ldst[wid][r][k];
            acc[r].x = fmaf(m.x, wl0.x, acc[r].x);
            acc[r].y = fmaf(m.x, wl0.y, acc[r].y);
            acc[r].x = fmaf(dd.x, wr0.x, acc[r].x);
            acc[r].y = fmaf(dd.x, wr0.y, acc[r].y);
            acc[r].x = fmaf(m.y, wl1.x, acc[r].x);
            acc[r].y = fmaf(m.y, wl1.y, acc[r].y);
            acc[r].x = fmaf(dd.y, wr1.x, acc[r].x);
            acc[r].y = fmaf(dd.y, wr1.y, acc[r].y);
        }
    }

    for (int r = 0; r < NPW; ++r) {
        int node = node0 + r;
        if (node < ndst) {
            float2 o = acc[r];
            o.x = fmaxf(o.x, 0.f); o.y = fmaxf(o.y, 0.f);
            __half2 hv = __floats2half2_rn(o.x, o.y);
            *(unsigned*)(out16 + (size_t)node * D + j0) = *(unsigned*)&hv;
        }
    }
}

// Layer 2 fused: z = mean @ Wl + b + xdst @ Wr (no relu), then
// P = z @ Wd (+ pb if given), stored fp32. z never hits global memory.
__global__ __launch_bounds__(256) void sage_l2_fused_kernel(
    const __half* __restrict__ xsrc, const __half* __restrict__ xdst,
    const int* __restrict__ off, const int* __restrict__ csr,
    const float* __restrict__ Wl, const float* __restrict__ Wr,
    const float* __restrict__ b, const float* __restrict__ Wd,
    const float* __restrict__ pb, float* __restrict__ Pout, int ndst)
{
    __shared__ __align__(16) float lmean[4][NPW][D];
    __shared__ __align__(16) float ldst[4][NPW][D];
    const int lane = threadIdx.x & 63;
    const int wid = threadIdx.x >> 6;
    const int j0 = lane * 2;
    const int node0 = (blockIdx.x * 4 + wid) * NPW;

    for (int r = 0; r < NPW; ++r) {
        int node = node0 + r;
        if (node >= ndst) break;
        int e0 = off[node], e1 = off[node + 1];
        int deg = e1 - e0;
        float2 acc; acc.x = 0.f; acc.y = 0.f;
        for (int base = e0; base < e1; base += 64) {
            int rem = e1 - base;
            int nv = rem < 64 ? rem : 64;
            int myidx = 0;
            if (lane < nv) myidx = csr[base + lane];
            int e = 0;
            int full = nv & ~7;
            for (; e < full; e += 8) {
                int s0 = __builtin_amdgcn_readlane(myidx, e + 0);
                int s1 = __builtin_amdgcn_readlane(myidx, e + 1);
                int s2 = __builtin_amdgcn_readlane(myidx, e + 2);
                int s3 = __builtin_amdgcn_readlane(myidx, e + 3);
                int s4 = __builtin_amdgcn_readlane(myidx, e + 4);
                int s5 = __builtin_amdgcn_readlane(myidx, e + 5);
                int s6 = __builtin_amdgcn_readlane(myidx, e + 6);
                int s7 = __builtin_amdgcn_readlane(myidx, e + 7);
                float2 v0 = __half22float2(*(const __half2*)(xsrc + (size_t)s0 * D + j0));
                float2 v1 = __half22float2(*(const __half2*)(xsrc + (size_t)s1 * D + j0));
                float2 v2 = __half22float2(*(const __half2*)(xsrc + (size_t)s2 * D + j0));
                float2 v3 = __half22float2(*(const __half2*)(xsrc + (size_t)s3 * D + j0));
                float2 v4 = __half22float2(*(const __half2*)(xsrc + (size_t)s4 * D + j0));
                float2 v5 = __half22float2(*(const __half2*)(xsrc + (size_t)s5 * D + j0));
                float2 v6 = __half22float2(*(const __half2*)(xsrc + (size_t)s6 * D + j0));
                float2 v7 = __half22float2(*(const __half2*)(xsrc + (size_t)s7 * D + j0));
                acc.x += ((v0.x + v1.x) + (v2.x + v3.x)) + ((v4.x + v5.x) + (v6.x + v7.x));
                acc.y += ((v0.y + v1.y) + (v2.y + v3.y)) + ((v4.y + v5.y) + (v6.y + v7.y));
            }
            for (; e < nv; ++e) {
                int s = __builtin_amdgcn_readlane(myidx, e);
                float2 v = __half22float2(*(const __half2*)(xsrc + (size_t)s * D + j0));
                acc.x += v.x; acc.y += v.y;
            }
        }
        float inv = 1.0f / (float)(deg < 1 ? 1 : deg);
        float2 xd = __half22float2(*(const __half2*)(xdst + (size_t)node * D + j0));
        lmean[wid][r][j0] = acc.x * inv;
        lmean[wid][r][j0 + 1] = acc.y * inv;
        ldst[wid][r][j0] = xd.x;
        ldst[wid][r][j0 + 1] = xd.y;
    }
    __syncthreads();

    float2 acc[NPW];
    float2 bv = *(const float2*)(b + j0);
    #pragma unroll
    for (int r = 0; r < NPW; ++r) acc[r] = bv;

    for (int k = 0; k < D; k += 2) {
        float2 wl0 = *(const float2*)(Wl + (size_t)k * D + j0);
        float2 wr0 = *(const float2*)(Wr + (size_t)k * D + j0);
        float2 wl1 = *(const float2*)(Wl + (size_t)(k + 1) * D + j0);
        float2 wr1 = *(const float2*)(Wr + (size_t)(k + 1) * D + j0);
        #pragma unroll
        for (int r = 0; r < NPW; ++r) {
            float2 m = *(const float2*)&lmean[wid][r][k];
            float2 dd = *(const float2*)&ldst[wid][r][k];
            acc[r].x = fmaf(m.x, wl0.x, acc[r].x);
            acc[r].y = fmaf(m.x, wl0.y, acc[r].y);
            acc[r].x = fmaf(dd.x, wr0.x, acc[r].x);
            acc[r].y = fmaf(dd.x, wr0.y, acc[r].y);
            acc[r].x = fmaf(m.y, wl1.x, acc[r].x);
            acc[r].y = fmaf(m.y, wl1.y, acc[r].y);
            acc[r].x = fmaf(dd.y, wr1.x, acc[r].x);
            acc[r].y = fmaf(dd.y, wr1.y, acc[r].y);
        }
    }

    // stash z back into lmean, then P = z @ Wd (+ pb)
    __syncthreads();
    #pragma unroll
    for (int r = 0; r < NPW; ++r) {
        lmean[wid][r][j0] = acc[r].x;
        lmean[wid][r][j0 + 1] = acc[r].y;
    }
    __syncthreads();

    float2 pacc[NPW];
    float2 pbv;
    if (pb) pbv = *(const float2*)(pb + j0);
    else { pbv.x = 0.f; pbv.y = 0.f; }
    #pragma unroll
    for (int r = 0; r < NPW; ++r) pacc[r] = pbv;

    for (int k = 0; k < D; k += 2) {
        float2 wd0 = *(const float2*)(Wd + (size_t)k * D + j0);
        float2 wd1 = *(const float2*)(Wd + (size_t)(k + 1) * D + j0);
        #pragma unroll
        for (int r = 0; r < NPW; ++r) {
            float2 z = *(const float2*)&lmean[wid][r][k];
            pacc[r].x = fmaf(z.x, wd0.x, pacc[r].x);
            pacc[r].y = fmaf(z.x, wd0.y, pacc[r].y);
            pacc[r].x = fmaf(z.y, wd1.x, pacc[r].x);
            pacc[r].y = fmaf(z.y, wd1.y, pacc[r].y);
        }
    }

    for (int r = 0; r < NPW; ++r) {
        int node = node0 + r;
        if (node < ndst)
            *(float2*)(Pout + (size_t)node * D + j0) = pacc[r];
    }
}

// ---------------- decoder: out[r] = sum_j relu(Pd[row][j]+Ps[col][j])*W2[j] + b2 ----------------
// Wave handles a 32-edge chunk; 16-lane group per edge, 4 edges in flight.

#define DEC_CHUNK 32

__global__ __launch_bounds__(256) void dec_gather_kernel(
    const float* __restrict__ Pd, const float* __restrict__ Ps,
    const int* __restrict__ row_idx, const int* __restrict__ col_idx,
    const float* __restrict__ W2, const float* __restrict__ b2,
    float* __restrict__ out, int nrows)
{
    const int lane = threadIdx.x & 63;
    const int wid = threadIdx.x >> 6;
    const int grp = lane >> 4;
    const int lr = lane & 15;
    const int wave_id = blockIdx.x * 4 + wid;
    const int e0 = wave_id * DEC_CHUNK;
    if (e0 >= nrows) return;

    int idx = (lane < 32) ? row_idx[e0 + lane] : col_idx[e0 + lane - 32];

    const int c0 = lr * 8;
    float w2v[8];
    #pragma unroll
    for (int i = 0; i < 8; ++i) w2v[i] = W2[c0 + i];
    float b2v = b2[0];

    #pragma unroll 2
    for (int it = 0; it < 8; ++it) {
        int ei = it * 4 + grp;
        int ri = __shfl(idx, ei, 64);
        int ci = __shfl(idx, 32 + ei, 64);
        float4 a0 = *(const float4*)(Pd + (size_t)ri * D + c0);
        float4 a1 = *(const float4*)(Pd + (size_t)ri * D + c0 + 4);
        float4 s0 = *(const float4*)(Ps + (size_t)ci * D + c0);
        float4 s1 = *(const float4*)(Ps + (size_t)ci * D + c0 + 4);
        float v;
        v = fmaxf(a0.x + s0.x, 0.f) * w2v[0];
        v = fmaf(fmaxf(a0.y + s0.y, 0.f), w2v[1], v);
        v = fmaf(fmaxf(a0.z + s0.z, 0.f), w2v[2], v);
        v = fmaf(fmaxf(a0.w + s0.w, 0.f), w2v[3], v);
        v = fmaf(fmaxf(a1.x + s1.x, 0.f), w2v[4], v);
        v = fmaf(fmaxf(a1.y + s1.y, 0.f), w2v[5], v);
        v = fmaf(fmaxf(a1.z + s1.z, 0.f), w2v[6], v);
        v = fmaf(fmaxf(a1.w + s1.w, 0.f), w2v[7], v);
        v += __shfl_xor(v, 1, 64);
        v += __shfl_xor(v, 2, 64);
        v += __shfl_xor(v, 4, 64);
        v += __shfl_xor(v, 8, 64);
        if (lr == 0) out[e0 + ei] = v + b2v;
    }
}

// ---------------- launcher ----------------

extern "C" void kernel_launch(void* const* d_in, const int* in_sizes, int n_in,
                              void* d_out, int out_size, void* d_ws, size_t ws_size,
                              hipStream_t stream) {
    const float* x_drug = (const float*)d_in[0];
    const float* x_dis  = (const float*)d_in[1];
    const int* ei_d2s = (const int*)d_in[2];
    const int* ei_s2d = (const int*)d_in[3];
    const int* ell    = (const int*)d_in[4];
    const float* W1l_d2s = (const float*)d_in[5];
    const float* W1r_d2s = (const float*)d_in[6];
    const float* W1l_s2d = (const float*)d_in[7];
    const float* W1r_s2d = (const float*)d_in[8];
    const float* W2l_d2s = (const float*)d_in[9];
    const float* W2r_d2s = (const float*)d_in[10];
    const float* W2l_s2d = (const float*)d_in[11];
    const float* W2r_s2d = (const float*)d_in[12];
    const float* b1_d2s = (const float*)d_in[13];
    const float* b1_s2d = (const float*)d_in[14];
    const float* b2_d2s = (const float*)d_in[15];
    const float* b2_s2d = (const float*)d_in[16];
    const float* dec_W1 = (const float*)d_in[17];
    const float* dec_b1 = (const float*)d_in[18];
    const float* dec_W2 = (const float*)d_in[19];
    const float* dec_b2 = (const float*)d_in[20];
    float* out = (float*)d_out;

    char* ws = (char*)d_ws;
    size_t o = 0;
    auto take = [&](size_t bytes) -> char* {
        char* p = ws + o;
        o += (bytes + 255) & ~(size_t)255;
        return p;
    };
    int* off_d2s = (int*)take((NDIS + 1) * sizeof(int));
    int* cur_d2s = (int*)take(NDIS * sizeof(int));
    int* csr_d2s = (int*)take((size_t)EDGES * sizeof(int));
    int* off_s2d = (int*)take((NDRUG + 1) * sizeof(int));
    int* cur_s2d = (int*)take(NDRUG * sizeof(int));
    int* csr_s2d = (int*)take((size_t)EDGES * sizeof(int));
    __half* x16_drug = (__half*)take((size_t)NDRUG * D * sizeof(__half));
    __half* x16_dis  = (__half*)take((size_t)NDIS * D * sizeof(__half));
    __half* h16_dis  = (__half*)take((size_t)NDIS * D * sizeof(__half));
    __half* h16_drug = (__half*)take((size_t)NDRUG * D * sizeof(__half));
    float* P_drug = (float*)take((size_t)NDRUG * D * sizeof(float));
    float* P_dis  = (float*)take((size_t)NDIS * D * sizeof(float));

    hipMemsetAsync(cur_d2s, 0, NDIS * sizeof(int), stream);
    hipMemsetAsync(cur_s2d, 0, NDRUG * sizeof(int), stream);

    const int EB = (EDGES + 255) / 256;
    hist_kernel<<<EB, 256, 0, stream>>>(ei_d2s + EDGES, cur_d2s, EDGES);
    hist_kernel<<<EB, 256, 0, stream>>>(ei_s2d + EDGES, cur_s2d, EDGES);
    scan2_kernel<<<2, 1024, 0, stream>>>(cur_d2s, off_d2s, cur_s2d, off_s2d, NDIS);
    scatter_kernel<<<EB, 256, 0, stream>>>(ei_d2s, ei_d2s + EDGES, cur_d2s, csr_d2s, EDGES);
    scatter_kernel<<<EB, 256, 0, stream>>>(ei_s2d, ei_s2d + EDGES, cur_s2d, csr_s2d, EDGES);

    // fp16 copies of input features
    cvt16_kernel<<<(NDRUG * D / 4 + 255) / 256, 256, 0, stream>>>(x_drug, x16_drug, NDRUG * D / 4);
    cvt16_kernel<<<(NDIS * D / 4 + 255) / 256, 256, 0, stream>>>(x_dis, x16_dis, NDIS * D / 4);

    // layer 1 (relu, fp16 out)
    sage_l1_kernel<<<1250, 256, 0, stream>>>(x16_drug, x16_dis, off_d2s, csr_d2s,
                                             W1l_d2s, W1r_d2s, b1_d2s, h16_dis, NDIS);
    sage_l1_kernel<<<1250, 256, 0, stream>>>(x16_dis, x16_drug, off_s2d, csr_s2d,
                                             W1l_s2d, W1r_s2d, b1_s2d, h16_drug, NDRUG);

    // layer 2 fused with decoder projection:
    //   P_dis  = (sage z_dis)  @ dec_W1[128:256] + dec_b1
    //   P_drug = (sage z_drug) @ dec_W1[0:128]
    sage_l2_fused_kernel<<<1250, 256, 0, stream>>>(h16_drug, h16_dis, off_d2s, csr_d2s,
                                                   W2l_d2s, W2r_d2s, b2_d2s,
                                                   dec_W1 + (size_t)D * D, dec_b1, P_dis, NDIS);
    sage_l2_fused_kernel<<<1250, 256, 0, stream>>>(h16_dis, h16_drug, off_s2d, csr_s2d,
                                                   W2l_s2d, W2r_s2d, b2_s2d,
                                                   dec_W1, nullptr, P_drug, NDRUG);

    // decoder gather: 200000/32 = 6250 waves -> 1563 blocks
    dec_gather_kernel<<<(LROWS / DEC_CHUNK + 3) / 4, 256, 0, stream>>>(
        P_drug, P_dis, ell, ell + LROWS, dec_W2, dec_b2, out, LROWS);
}